// Round 11
// baseline (402.145 us; speedup 1.0000x reference)
//
#include <hip/hip_runtime.h>
#include <math.h>

namespace {
constexpr int kT = 8, kL = 8, kN = 500, kD = 64, kK = 12;
constexpr int kLN  = kL * kN;        // 4000
constexpr int kTLN = kT * kL * kN;   // 32000
constexpr int kBUF = kTLN * kD;      // 2,048,000 elements
constexpr int XS = 68;               // padded LDS stride for X tiles
}

__device__ __forceinline__ float sigf(float v) { return 1.f / (1.f + __expf(-v)); }

__device__ __forceinline__ uint2 pack_bf16x4(float4 v) {
    auto r = [](float f) {
        unsigned u = __float_as_uint(f);
        u += 0x7FFFu + ((u >> 16) & 1u);
        return u >> 16;
    };
    uint2 o;
    o.x = r(v.x) | (r(v.y) << 16);
    o.y = r(v.z) | (r(v.w) << 16);
    return o;
}

__device__ __forceinline__ float4 unpack_bf16x4(uint2 kk) {
    float4 f;
    f.x = __uint_as_float(kk.x << 16);
    f.y = __uint_as_float(kk.x & 0xFFFF0000u);
    f.z = __uint_as_float(kk.y << 16);
    f.w = __uint_as_float(kk.y & 0xFFFF0000u);
    return f;
}

// WAVE-ALIGNED staging: wave w stages LDS rows [16w,16w+16) -> no barrier needed.
__device__ __forceinline__ void stage_x_wave(const float* __restrict__ src, float* lds,
                                             int row0, int M) {
    int lane = threadIdx.x & 63, w = threadIdx.x >> 6;
    int rr = 16 * w + (lane >> 2);
    int row = row0 + rr;
    row = row < M ? row : M - 1;
    int f0 = lane & 3;
#pragma unroll
    for (int i = 0; i < 4; ++i) {
        int f = f0 + 4 * i;
        float4 v = *reinterpret_cast<const float4*>(src + (size_t)row * 64 + f * 4);
        *reinterpret_cast<float4*>(lds + rr * XS + f * 4) = v;
    }
}

__device__ __forceinline__ void stage_x_bf16_wave(const unsigned short* __restrict__ src,
                                                  float* lds, int row0) {
    int lane = threadIdx.x & 63, w = threadIdx.x >> 6;
    int rr = 16 * w + (lane >> 2);
    int f0 = lane & 3;
#pragma unroll
    for (int i = 0; i < 4; ++i) {
        int f = f0 + 4 * i;
        uint2 v = *reinterpret_cast<const uint2*>(src + (size_t)(row0 + rr) * 64 + f * 4);
        *reinterpret_cast<float4*>(lds + rr * XS + f * 4) = unpack_bf16x4(v);
    }
}

template <int K>
__device__ __forceinline__ void stage_w(const float* __restrict__ w, float* lds) {
    const float4* s = reinterpret_cast<const float4*>(w);
    float4* d = reinterpret_cast<float4*>(lds);
#pragma unroll
    for (int i = 0; i < K / 16; ++i)
        d[threadIdx.x + 256 * i] = s[threadIdx.x + 256 * i];
}

// acc[i] += row(4*rblk+i) of Xtile @ W[:, 4*cblk..+3], K=64.
__device__ __forceinline__ void gemm_core(const float* ldsx, const float* w,
                                          int rblk, int cblk, float4 acc[4]) {
#pragma unroll 4
    for (int k = 0; k < 64; k += 4) {
        float4 xv[4], wv[4];
#pragma unroll
        for (int i = 0; i < 4; ++i)
            xv[i] = *reinterpret_cast<const float4*>(ldsx + (4 * rblk + i) * XS + k);
#pragma unroll
        for (int d = 0; d < 4; ++d)
            wv[d] = *reinterpret_cast<const float4*>(w + (k + d) * 64 + 4 * cblk);
#pragma unroll
        for (int i = 0; i < 4; ++i) {
            float xs[4] = {xv[i].x, xv[i].y, xv[i].z, xv[i].w};
#pragma unroll
            for (int d = 0; d < 4; ++d) {
                acc[i].x = fmaf(xs[d], wv[d].x, acc[i].x);
                acc[i].y = fmaf(xs[d], wv[d].y, acc[i].y);
                acc[i].z = fmaf(xs[d], wv[d].z, acc[i].z);
                acc[i].w = fmaf(xs[d], wv[d].w, acc[i].w);
            }
        }
    }
}

// Triple-weight version sharing the X reads (weights global/L1-L2).
__device__ __forceinline__ void gemm_core3(const float* ldsx, const float* wa,
                                           const float* wb, const float* wc,
                                           int rblk, int cblk,
                                           float4 aa[4], float4 ab[4], float4 ac[4]) {
#pragma unroll 2
    for (int k = 0; k < 64; k += 4) {
        float4 xv[4], va[4], vb[4], vc[4];
#pragma unroll
        for (int i = 0; i < 4; ++i)
            xv[i] = *reinterpret_cast<const float4*>(ldsx + (4 * rblk + i) * XS + k);
#pragma unroll
        for (int d = 0; d < 4; ++d) {
            va[d] = *reinterpret_cast<const float4*>(wa + (k + d) * 64 + 4 * cblk);
            vb[d] = *reinterpret_cast<const float4*>(wb + (k + d) * 64 + 4 * cblk);
            vc[d] = *reinterpret_cast<const float4*>(wc + (k + d) * 64 + 4 * cblk);
        }
#pragma unroll
        for (int i = 0; i < 4; ++i) {
            float xs[4] = {xv[i].x, xv[i].y, xv[i].z, xv[i].w};
#pragma unroll
            for (int d = 0; d < 4; ++d) {
                aa[i].x = fmaf(xs[d], va[d].x, aa[i].x);
                aa[i].y = fmaf(xs[d], va[d].y, aa[i].y);
                aa[i].z = fmaf(xs[d], va[d].z, aa[i].z);
                aa[i].w = fmaf(xs[d], va[d].w, aa[i].w);
                ab[i].x = fmaf(xs[d], vb[d].x, ab[i].x);
                ab[i].y = fmaf(xs[d], vb[d].y, ab[i].y);
                ab[i].z = fmaf(xs[d], vb[d].z, ab[i].z);
                ab[i].w = fmaf(xs[d], vb[d].w, ab[i].w);
                ac[i].x = fmaf(xs[d], vc[d].x, ac[i].x);
                ac[i].y = fmaf(xs[d], vc[d].y, ac[i].y);
                ac[i].z = fmaf(xs[d], vc[d].z, ac[i].z);
                ac[i].w = fmaf(xs[d], vc[d].w, ac[i].w);
            }
        }
    }
}

// 64x64 fp32 GEMM, Out = A @ B (all global, row-major). One block, 256 threads.
__device__ __forceinline__ void small_gemm_nn(const float* __restrict__ A,
                                              const float* __restrict__ B,
                                              float* __restrict__ Out) {
    int rblk = threadIdx.x >> 4, cblk = threadIdx.x & 15;
    float4 acc[4] = {};
#pragma unroll 4
    for (int k = 0; k < 64; k += 4) {
        float4 a[4], b[4];
#pragma unroll
        for (int i = 0; i < 4; ++i)
            a[i] = *reinterpret_cast<const float4*>(A + (4 * rblk + i) * 64 + k);
#pragma unroll
        for (int d = 0; d < 4; ++d)
            b[d] = *reinterpret_cast<const float4*>(B + (k + d) * 64 + 4 * cblk);
#pragma unroll
        for (int i = 0; i < 4; ++i) {
            float xs[4] = {a[i].x, a[i].y, a[i].z, a[i].w};
#pragma unroll
            for (int d = 0; d < 4; ++d) {
                acc[i].x = fmaf(xs[d], b[d].x, acc[i].x);
                acc[i].y = fmaf(xs[d], b[d].y, acc[i].y);
                acc[i].z = fmaf(xs[d], b[d].z, acc[i].z);
                acc[i].w = fmaf(xs[d], b[d].w, acc[i].w);
            }
        }
    }
#pragma unroll
    for (int i = 0; i < 4; ++i)
        *reinterpret_cast<float4*>(Out + (4 * rblk + i) * 64 + 4 * cblk) = acc[i];
}

// Out = A @ B^T  (Out[i][j] = sum_k A[i][k]*B[j][k]).
__device__ __forceinline__ void small_gemm_nt(const float* __restrict__ A,
                                              const float* __restrict__ B,
                                              float* __restrict__ Out) {
    int rblk = threadIdx.x >> 4, cblk = threadIdx.x & 15;
    float4 acc[4] = {};
#pragma unroll 4
    for (int k = 0; k < 64; k += 4) {
        float4 a[4], b[4];
#pragma unroll
        for (int i = 0; i < 4; ++i)
            a[i] = *reinterpret_cast<const float4*>(A + (4 * rblk + i) * 64 + k);
#pragma unroll
        for (int j = 0; j < 4; ++j)
            b[j] = *reinterpret_cast<const float4*>(B + (4 * cblk + j) * 64 + k);
#pragma unroll
        for (int i = 0; i < 4; ++i) {
            acc[i].x += a[i].x * b[0].x + a[i].y * b[0].y + a[i].z * b[0].z + a[i].w * b[0].w;
            acc[i].y += a[i].x * b[1].x + a[i].y * b[1].y + a[i].z * b[1].z + a[i].w * b[1].w;
            acc[i].z += a[i].x * b[2].x + a[i].y * b[2].y + a[i].z * b[2].z + a[i].w * b[2].w;
            acc[i].w += a[i].x * b[3].x + a[i].y * b[3].y + a[i].z * b[3].z + a[i].w * b[3].w;
        }
    }
#pragma unroll
    for (int i = 0; i < 4; ++i)
        *reinterpret_cast<float4*>(Out + (4 * rblk + i) * 64 + 4 * cblk) = acc[i];
}

// Evolution scan (blocks 0..62) + weight-product prep (blocks 63..98):
// per (c,step) combo cs in [0,12): M = wq@wk^T, wqd = wq@wd, wkd = wk@wd.
__global__ void __launch_bounds__(256) evo_wprep_kernel(const float* __restrict__ stat,
                                                        const float* __restrict__ thre,
                                                        const float* __restrict__ dyn0,
                                                        float* __restrict__ all_dyn,
                                                        float* __restrict__ diff,
                                                        float* __restrict__ now_final,
                                                        const float* __restrict__ w1,
                                                        const float* __restrict__ wq_all,
                                                        const float* __restrict__ wk_all,
                                                        const float* __restrict__ wd_all,
                                                        float* __restrict__ wpM,
                                                        float* __restrict__ wpQ,
                                                        float* __restrict__ wpK) {
    __shared__ float ldsn[64 * XS];
    __shared__ float ldss[64 * XS];
    __shared__ float ldsw[128 * 64];
    if (blockIdx.x >= 63) {
        int i = blockIdx.x - 63;        // 0..35
        int kind = i % 3;
        size_t cs = (size_t)(i / 3) * kD * kD;
        if (kind == 0)      small_gemm_nt(wq_all + cs, wk_all + cs, wpM + cs);
        else if (kind == 1) small_gemm_nn(wq_all + cs, wd_all + cs, wpQ + cs);
        else                small_gemm_nn(wk_all + cs, wd_all + cs, wpK + cs);
        return;
    }
    int row0 = blockIdx.x * 64;
    stage_x_wave(dyn0, ldsn, row0, kLN);
    stage_w<128>(w1, ldsw);
    int rblk = threadIdx.x >> 4, cblk = threadIdx.x & 15;
    __syncthreads();   // w1 shared across waves; X rows wave-local
#pragma unroll
    for (int i = 0; i < 4; ++i) {
        int row = row0 + 4 * rblk + i;
        if (row < kLN) {
            float4 x0 = *reinterpret_cast<const float4*>(ldsn + (4 * rblk + i) * XS + 4 * cblk);
            *reinterpret_cast<float4*>(all_dyn + (size_t)row * 64 + 4 * cblk) = x0;
        }
    }
#pragma unroll 1
    for (int t = 1; t < kT; ++t) {
        stage_x_wave(stat + (size_t)t * kLN * kD, ldss, row0, kLN);
        float4 acc[4] = {};
        gemm_core(ldsn, ldsw, rblk, cblk, acc);
        gemm_core(ldss, ldsw + 64 * 64, rblk, cblk, acc);
        float4 nv[4];
#pragma unroll
        for (int i = 0; i < 4; ++i) {
            int row = row0 + 4 * rblk + i;
            int rc  = row < kLN ? row : kLN - 1;
            float tt = thre[t * kLN + rc];
            float4 xn = *reinterpret_cast<const float4*>(ldsn + (4 * rblk + i) * XS + 4 * cblk);
            nv[i].x = sigf(acc[i].x * tt + xn.x * (1.f - tt));
            nv[i].y = sigf(acc[i].y * tt + xn.y * (1.f - tt));
            nv[i].z = sigf(acc[i].z * tt + xn.z * (1.f - tt));
            nv[i].w = sigf(acc[i].w * tt + xn.w * (1.f - tt));
            if (row < kLN) {
                float4 df;
                df.x = nv[i].x - xn.x; df.y = nv[i].y - xn.y;
                df.z = nv[i].z - xn.z; df.w = nv[i].w - xn.w;
                *reinterpret_cast<float4*>(all_dyn + ((size_t)t * kLN + row) * 64 + 4 * cblk) = nv[i];
                *reinterpret_cast<float4*>(diff + ((size_t)(t - 1) * kLN + row) * 64 + 4 * cblk) = df;
                if (t == kT - 1)
                    *reinterpret_cast<float4*>(now_final + (size_t)row * 64 + 4 * cblk) = nv[i];
            }
        }
#pragma unroll
        for (int i = 0; i < 4; ++i)
            *reinterpret_cast<float4*>(ldsn + (4 * rblk + i) * XS + 4 * cblk) = nv[i];
    }
}

// Projections: P = X@M, QD = X@(wq wd), KD = X@(wk wd). One X staging, three
// outputs (all bf16). Barrier-free (wave-aligned staging). 6 chains batched.
__global__ void __launch_bounds__(256) proj_kernel(const float* __restrict__ Xdyn,
                                                   const float* __restrict__ Xstat,
                                                   const unsigned short* __restrict__ b_y,
                                                   const float* __restrict__ wpM,
                                                   const float* __restrict__ wpQ,
                                                   const float* __restrict__ wpK,
                                                   unsigned short* __restrict__ b_p,
                                                   unsigned short* __restrict__ b_qd,
                                                   unsigned short* __restrict__ b_kd,
                                                   int step) {
    __shared__ float ldsx[64 * XS];
    int c = blockIdx.y;
    int m = c / 3;
    size_t cs = (size_t)(c * 2 + step) * kD * kD;
    int row0 = blockIdx.x * 64;
    if (step) stage_x_bf16_wave(b_y + (size_t)c * kBUF, ldsx, row0);
    else      stage_x_wave(m == 0 ? Xdyn : Xstat, ldsx, row0, kTLN);
    int rblk = threadIdx.x >> 4, cblk = threadIdx.x & 15;
    float4 aP[4] = {}, aQ[4] = {}, aK[4] = {};
    gemm_core3(ldsx, wpM + cs, wpQ + cs, wpK + cs, rblk, cblk, aP, aQ, aK);
    unsigned short* pc  = b_p  + (size_t)c * kBUF;
    unsigned short* qc  = b_qd + (size_t)c * kBUF;
    unsigned short* kc  = b_kd + (size_t)c * kBUF;
#pragma unroll
    for (int i = 0; i < 4; ++i) {
        size_t row = row0 + 4 * rblk + i;
        *reinterpret_cast<uint2*>(pc + row * 64 + 4 * cblk) = pack_bf16x4(aP[i]);
        *reinterpret_cast<uint2*>(qc + row * 64 + 4 * cblk) = pack_bf16x4(aQ[i]);
        *reinterpret_cast<uint2*>(kc + row * 64 + 4 * cblk) = pack_bf16x4(aK[i]);
    }
}

// Pure-streaming score kernel: NO LDS, NO barrier, NO GEMM. Per row:
// sc_j = P_row . x_j (gather input x); softmax; y = sigmoid(QD_row + sum a_j KD_j).
// KD gathers issued before the butterfly to overlap latency. XCD-swizzled.
__global__ void __launch_bounds__(256) score_kernel(const unsigned short* __restrict__ b_p,
                                                    const unsigned short* __restrict__ b_qd,
                                                    const unsigned short* __restrict__ b_kd,
                                                    const float* __restrict__ Xdyn,
                                                    const float* __restrict__ Xstat,
                                                    const unsigned short* __restrict__ b_y_in,
                                                    unsigned short* __restrict__ Ybase,
                                                    const int* __restrict__ npoi,
                                                    const int* __restrict__ nroad,
                                                    const int* __restrict__ nrec,
                                                    int step) {
    int p   = blockIdx.y * gridDim.x + blockIdx.x;
    int xcd = p & 7;
    int gid = xcd * 375 + (p >> 3);      // 0..2999
    int c    = gid / 500;
    int tile = gid - c * 500;
    int m = c / 3, g = c % 3;
    const uint2* P  = reinterpret_cast<const uint2*>(b_p  + (size_t)c * kBUF);
    const uint2* QD = reinterpret_cast<const uint2*>(b_qd + (size_t)c * kBUF);
    const uint2* KD = reinterpret_cast<const uint2*>(b_kd + (size_t)c * kBUF);
    const float* Xf = (m == 0) ? Xdyn : Xstat;
    const uint2* Xb = reinterpret_cast<const uint2*>(b_y_in + (size_t)c * kBUF);
    unsigned short* Y = Ybase + (size_t)c * kBUF;
    const int* neigh = (g == 0) ? npoi : (g == 1) ? nroad : nrec;
    int lane = threadIdx.x & 63;
    int wv   = threadIdx.x >> 6;
    int sub  = lane >> 4;
    int gq   = lane & 15;
    int row0 = tile * 64;
#pragma unroll 1
    for (int pp = 0; pp < 4; ++pp) {
        int row = row0 + pp * 16 + wv * 4 + sub;
        int n   = row % kN;
        int slab = row - n;
        const int4* nbp = reinterpret_cast<const int4*>(neigh + n * kK);
        int4 nb0 = nbp[0], nb1 = nbp[1], nb2 = nbp[2];
        int nb[12] = {nb0.x, nb0.y, nb0.z, nb0.w, nb1.x, nb1.y, nb1.z, nb1.w,
                      nb2.x, nb2.y, nb2.z, nb2.w};
        // fire KD gathers early (consumed after softmax)
        uint2 kdr[12];
#pragma unroll
        for (int j = 0; j < 12; ++j)
            kdr[j] = KD[(size_t)(slab + nb[j]) * 16 + gq];
        float4 pv = unpack_bf16x4(P[(size_t)row * 16 + gq]);
        float sc[12];
        if (step == 0) {
#pragma unroll
            for (int j = 0; j < 12; ++j) {
                float4 xj = *(reinterpret_cast<const float4*>(Xf) + (size_t)(slab + nb[j]) * 16 + gq);
                sc[j] = pv.x * xj.x + pv.y * xj.y + pv.z * xj.z + pv.w * xj.w;
            }
        } else {
#pragma unroll
            for (int j = 0; j < 12; ++j) {
                float4 xj = unpack_bf16x4(Xb[(size_t)(slab + nb[j]) * 16 + gq]);
                sc[j] = pv.x * xj.x + pv.y * xj.y + pv.z * xj.z + pv.w * xj.w;
            }
        }
#pragma unroll
        for (int off = 1; off < 16; off <<= 1) {
#pragma unroll
            for (int j = 0; j < 12; ++j) sc[j] += __shfl_xor(sc[j], off, 16);
        }
        float mx = sc[0];
#pragma unroll
        for (int j = 1; j < 12; ++j) mx = fmaxf(mx, sc[j]);
        float ssum = 0.f;
#pragma unroll
        for (int j = 0; j < 12; ++j) { sc[j] = __expf(sc[j] - mx); ssum += sc[j]; }
        float inv = 1.f / ssum;
        float4 o = unpack_bf16x4(QD[(size_t)row * 16 + gq]);
#pragma unroll
        for (int j = 0; j < 12; ++j) {
            float a = sc[j] * inv;
            float4 kd = unpack_bf16x4(kdr[j]);
            o.x = fmaf(a, kd.x, o.x);
            o.y = fmaf(a, kd.y, o.y);
            o.z = fmaf(a, kd.z, o.z);
            o.w = fmaf(a, kd.w, o.w);
        }
        float4 y;
        y.x = sigf(o.x); y.y = sigf(o.y); y.z = sigf(o.z); y.w = sigf(o.w);
        *reinterpret_cast<uint2*>(Y + (size_t)row * 64 + 4 * gq) = pack_bf16x4(y);
    }
}

// LSTM with mix fused: reads the 6 bf16 y buffers + wmix per l-step.
__global__ void __launch_bounds__(256) lstm_kernel(const unsigned short* __restrict__ b1,
                                                   const float* __restrict__ wmix,
                                                   const float* __restrict__ cw,
                                                   const float* __restrict__ cb,
                                                   float* __restrict__ hlast) {
    int lane = threadIdx.x & 63;
    int wv   = threadIdx.x >> 6;
    int sub  = lane >> 4;
    int fq   = lane & 15;
    int cell = blockIdx.x * 16 + wv * 4 + sub;   // 0..3999
    int t = cell / kN, n = cell % kN;
    float wd_[4][4], ws_[4][4], wh[4], bb[4];
#pragma unroll
    for (int gg = 0; gg < 4; ++gg) {
#pragma unroll
        for (int k = 0; k < 4; ++k) {
            wd_[gg][k] = cw[gg * 129 + fq * 4 + k];
            ws_[gg][k] = cw[gg * 129 + 64 + fq * 4 + k];
        }
        wh[gg] = cw[gg * 129 + 128];
        bb[gg] = cb[gg];
    }
    float4 wm[6];
#pragma unroll
    for (int j = 0; j < 6; ++j)
        wm[j] = *reinterpret_cast<const float4*>(wmix + j * 64 + fq * 4);
    float h = 0.f, cc = 0.f;
#pragma unroll 1
    for (int l = 0; l < kL; ++l) {
        size_t base = ((size_t)(t * kL + l) * kN + n) * 64 + fq * 4;
        float4 y[6];
#pragma unroll
        for (int j = 0; j < 6; ++j)
            y[j] = unpack_bf16x4(*reinterpret_cast<const uint2*>(b1 + (size_t)j * kBUF + base));
        float4 xd, xs;
        xd.x = sigf(y[0].x * wm[0].x + y[1].x * wm[1].x + y[2].x * wm[2].x);
        xd.y = sigf(y[0].y * wm[0].y + y[1].y * wm[1].y + y[2].y * wm[2].y);
        xd.z = sigf(y[0].z * wm[0].z + y[1].z * wm[1].z + y[2].z * wm[2].z);
        xd.w = sigf(y[0].w * wm[0].w + y[1].w * wm[1].w + y[2].w * wm[2].w);
        xs.x = sigf(y[3].x * wm[3].x + y[4].x * wm[4].x + y[5].x * wm[5].x);
        xs.y = sigf(y[3].y * wm[3].y + y[4].y * wm[4].y + y[5].y * wm[5].y);
        xs.z = sigf(y[3].z * wm[3].z + y[4].z * wm[4].z + y[5].z * wm[5].z);
        xs.w = sigf(y[3].w * wm[3].w + y[4].w * wm[4].w + y[5].w * wm[5].w);
        float gsum[4];
#pragma unroll
        for (int gg = 0; gg < 4; ++gg) {
            float v = xd.x * wd_[gg][0] + xd.y * wd_[gg][1]
                    + xd.z * wd_[gg][2] + xd.w * wd_[gg][3];
            v += xs.x * ws_[gg][0] + xs.y * ws_[gg][1]
               + xs.z * ws_[gg][2] + xs.w * ws_[gg][3];
            gsum[gg] = v;
        }
#pragma unroll
        for (int off = 1; off < 16; off <<= 1) {
#pragma unroll
            for (int gg = 0; gg < 4; ++gg) gsum[gg] += __shfl_xor(gsum[gg], off, 16);
        }
        float gi = sigf(gsum[0] + bb[0] + h * wh[0]);
        float gf = sigf(gsum[1] + bb[1] + h * wh[1]);
        float go = sigf(gsum[2] + bb[2] + h * wh[2]);
        float gg_ = tanhf(gsum[3] + bb[3] + h * wh[3]);
        cc = gf * cc + gi * gg_;
        h = go * tanhf(cc);
    }
    if (fq == 0) hlast[cell] = h;
}

// out[t,m] = sigmoid(sum_n h[t,n]*fw[m,n] + fb[m]); one wave per output.
__global__ void final_kernel(const float* __restrict__ h, const float* __restrict__ fw,
                             const float* __restrict__ fb, float* __restrict__ out) {
    int wave = threadIdx.x >> 6, lane = threadIdx.x & 63;
    int o = blockIdx.x * 4 + wave;
    int t = o / kN, m = o % kN;
    float acc = 0.f;
    for (int n = lane; n < kN; n += 64)
        acc = fmaf(h[t * kN + n], fw[(size_t)m * kN + n], acc);
#pragma unroll
    for (int off = 32; off > 0; off >>= 1) acc += __shfl_xor(acc, off);
    if (lane == 0) out[o] = sigf(acc + fb[m]);
}

extern "C" void kernel_launch(void* const* d_in, const int* in_sizes, int n_in,
                              void* d_out, int out_size, void* d_ws, size_t ws_size,
                              hipStream_t stream) {
    const float* stat   = (const float*)d_in[0];
    const float* thre   = (const float*)d_in[1];
    const float* dyn0   = (const float*)d_in[2];
    const int*   npoi   = (const int*)d_in[3];
    const int*   nroad  = (const int*)d_in[4];
    const int*   nrec   = (const int*)d_in[5];
    const float* w1     = (const float*)d_in[6];
    const float* wq_all = (const float*)d_in[7];
    const float* wk_all = (const float*)d_in[8];
    const float* wd_all = (const float*)d_in[9];
    const float* wmix   = (const float*)d_in[10];
    const float* conv_w = (const float*)d_in[11];
    const float* conv_b = (const float*)d_in[12];
    const float* fin_w  = (const float*)d_in[13];
    const float* fin_b  = (const float*)d_in[14];

    float* out       = (float*)d_out;                 // (T,N)
    float* now_final = out + kT * kN;                 // (L,N,D)
    float* diffs     = now_final + (size_t)kLN * kD;  // (T-1,L,N,D)

    float* ws      = (float*)d_ws;
    float* all_dyn = ws;                                            // kBUF fp32
    unsigned short* b_qd = (unsigned short*)(ws + (size_t)kBUF);    // 6 x kBUF bf16
    unsigned short* b_p  = (unsigned short*)(ws + 4 * (size_t)kBUF);
    unsigned short* b_kd = (unsigned short*)(ws + 7 * (size_t)kBUF);
    unsigned short* b_y  = (unsigned short*)(ws + 10 * (size_t)kBUF);
    float* wpM   = ws + 13 * (size_t)kBUF;            // 12 x 4096 fp32 each
    float* wpQ   = wpM + 12 * 4096;
    float* wpK   = wpQ + 12 * 4096;
    float* hlast = wpK + 12 * 4096;                   // (T,N)

    // ---- evolution scan + weight-product prep (one launch) ----
    evo_wprep_kernel<<<63 + 36, 256, 0, stream>>>(stat, thre, dyn0, all_dyn, diffs,
                                                  now_final, w1, wq_all, wk_all, wd_all,
                                                  wpM, wpQ, wpK);

    // ---- attention: proj (P,QD,KD) then streaming score, 2 steps ----
    dim3 agrid(kTLN / 64, 6);
    proj_kernel<<<agrid, 256, 0, stream>>>(all_dyn, stat, b_y, wpM, wpQ, wpK,
                                           b_p, b_qd, b_kd, 0);
    score_kernel<<<agrid, 256, 0, stream>>>(b_p, b_qd, b_kd, all_dyn, stat, b_y,
                                            b_y, npoi, nroad, nrec, 0);
    proj_kernel<<<agrid, 256, 0, stream>>>(all_dyn, stat, b_y, wpM, wpQ, wpK,
                                           b_p, b_qd, b_kd, 1);
    score_kernel<<<agrid, 256, 0, stream>>>(b_p, b_qd, b_kd, all_dyn, stat, b_y,
                                            b_qd, npoi, nroad, nrec, 1);

    // ---- LSTM (mix fused, reads y1 = b_qd) then final projection ----
    lstm_kernel<<<kT * kN / 16, 256, 0, stream>>>(b_qd, wmix, conv_w, conv_b, hlast);
    final_kernel<<<kT * kN / 4, 256, 0, stream>>>(hlast, fin_w, fin_b, out);
}